// Round 4
// baseline (148.491 us; speedup 1.0000x reference)
//
#include <hip/hip_runtime.h>
#include <math.h>

// N=65536 rows, D=256 fp32. out = sum_i (counts_i - 1)*d_i + exp(d_i)
// d_i = dot(z_a[i], z_b[i]); counts_i-1 = n-3 (i < n-1), n-2 (i == n-1).
//
// R1: 2 loads in flight/wave -> 42 us (latency-bound).
// R2: atomicAdd serialization + still-serialized loads -> 62 us.
// R3: VGPR_Count=32 proved the allocator flattened the 16-load batch
//     back into a serial chain -> 44 us.
// R4: explicit double-buffered pipeline: prefetch batch k+1's 8 loads
//     (pinned with sched_barrier) before reducing batch k, so compute
//     waits only on vmcnt(8) and 8 KiB/wave stays in flight.

#define D_DIM 256
#define BATCH 4            // rows per batch
#define BATCHES 4          // batches per wave -> 16 rows/wave
#define BLOCKS 1024        // 1024 blk * 4 waves * 16 rows = 65536 exactly

__global__ __launch_bounds__(256, 4)
void dot_loss_partial(const float4* __restrict__ za4,
                      const float4* __restrict__ zb4,
                      float* __restrict__ partial,
                      int n) {
    const int lane = threadIdx.x & 63;
    const int wave = threadIdx.x >> 6;
    const int waveId = blockIdx.x * 4 + wave;
    const int row0 = waveId * (BATCH * BATCHES);

    const float4* a = za4 + (size_t)row0 * 64 + lane;
    const float4* b = zb4 + (size_t)row0 * 64 + lane;

    float4 av[2][BATCH], bv[2][BATCH];

    // Prologue: issue batch 0's 8 loads.
    #pragma unroll
    for (int r = 0; r < BATCH; ++r) {
        av[0][r] = a[(size_t)r * 64];
        bv[0][r] = b[(size_t)r * 64];
    }

    float acc = 0.0f;

    #pragma unroll
    for (int batch = 0; batch < BATCHES; ++batch) {
        const int buf = batch & 1;
        const int nbuf = buf ^ 1;

        // Prefetch next batch BEFORE touching current batch's data.
        if (batch < BATCHES - 1) {
            const size_t base = (size_t)(batch + 1) * BATCH * 64;
            #pragma unroll
            for (int r = 0; r < BATCH; ++r) {
                av[nbuf][r] = a[base + (size_t)r * 64];
                bv[nbuf][r] = b[base + (size_t)r * 64];
            }
        }
        // Pin: everything above (the prefetch issues) stays above.
        __builtin_amdgcn_sched_barrier(0);

        float d[BATCH];
        #pragma unroll
        for (int r = 0; r < BATCH; ++r) {
            float t = av[buf][r].x * bv[buf][r].x;
            t = fmaf(av[buf][r].y, bv[buf][r].y, t);
            t = fmaf(av[buf][r].z, bv[buf][r].z, t);
            t = fmaf(av[buf][r].w, bv[buf][r].w, t);
            d[r] = t;
        }

        // 4 independent wave-64 reduction chains, interleaved.
        #pragma unroll
        for (int off = 32; off > 0; off >>= 1) {
            #pragma unroll
            for (int r = 0; r < BATCH; ++r)
                d[r] += __shfl_down(d[r], off);
        }

        if (lane == 0) {
            #pragma unroll
            for (int r = 0; r < BATCH; ++r) {
                int row = row0 + batch * BATCH + r;
                float coeff = (row == n - 1) ? (float)(n - 2) : (float)(n - 3);
                acc += coeff * d[r] + expf(d[r]);
            }
        }
    }

    __shared__ float smem[4];
    if (lane == 0) smem[wave] = acc;
    __syncthreads();
    if (threadIdx.x == 0)
        partial[blockIdx.x] = smem[0] + smem[1] + smem[2] + smem[3];
}

__global__ __launch_bounds__(256)
void reduce_partials(const float* __restrict__ partial,
                     float* __restrict__ out,
                     int m) {
    const int lane = threadIdx.x & 63;
    const int wave = threadIdx.x >> 6;
    double s = 0.0;
    for (int i = threadIdx.x; i < m; i += 256)
        s += (double)partial[i];
    #pragma unroll
    for (int off = 32; off > 0; off >>= 1)
        s += __shfl_down(s, off);
    __shared__ double smem[4];
    if (lane == 0) smem[wave] = s;
    __syncthreads();
    if (threadIdx.x == 0)
        out[0] = (float)(smem[0] + smem[1] + smem[2] + smem[3]);
}

extern "C" void kernel_launch(void* const* d_in, const int* in_sizes, int n_in,
                              void* d_out, int out_size, void* d_ws, size_t ws_size,
                              hipStream_t stream) {
    const float4* za4 = (const float4*)d_in[0];
    const float4* zb4 = (const float4*)d_in[1];
    float* out = (float*)d_out;
    float* partial = (float*)d_ws;   // BLOCKS floats of scratch
    const int n = in_sizes[0] / D_DIM;

    dot_loss_partial<<<BLOCKS, 256, 0, stream>>>(za4, zb4, partial, n);
    reduce_partials<<<1, 256, 0, stream>>>(partial, out, BLOCKS);
}

// Round 5
// 143.640 us; speedup vs baseline: 1.0338x; 1.0338x over previous
//
#include <hip/hip_runtime.h>
#include <math.h>

// N=65536 rows, D=256 fp32. out = sum_i (counts_i - 1)*d_i + exp(d_i)
// d_i = dot(z_a[i], z_b[i]); counts_i-1 = n-3 (i < n-1), n-2 (i == n-1).
//
// R1/R3/R4 all ~44 us regardless of batching/occupancy: the per-row
// dependent 6-step __shfl_down chain (DS-pipe latency) serialized each
// wave; VGPR allocator kept collapsing load batches held for shuffles.
// R5: LDS-transpose reduction. Phase 1: stream load->dot4->ds_write
// (no cross-lane ops, fully pipelineable). Phase 2: transpose read
// (stride-65 pad -> 2-way bank aliasing = free), one shfl to merge
// halves, vectorized exp over 32 rows at once.

#define D_DIM 256
#define ROWS_PER_WAVE 32
#define WAVES_PER_BLOCK 4
// blocks = n / (ROWS_PER_WAVE * WAVES_PER_BLOCK) = 65536/128 = 512

__global__ __launch_bounds__(256, 2)
void dot_loss_partial(const float4* __restrict__ za4,
                      const float4* __restrict__ zb4,
                      float* __restrict__ partial,
                      int n) {
    const int lane = threadIdx.x & 63;
    const int wave = threadIdx.x >> 6;
    const int waveId = blockIdx.x * WAVES_PER_BLOCK + wave;
    const int row0 = waveId * ROWS_PER_WAVE;

    // part[wave][row][lane] with stride 65: write banks (row+lane)%32 and
    // transpose-read banks (row+col)%32 are both exactly 2-way aliased (free).
    __shared__ float part[WAVES_PER_BLOCK][ROWS_PER_WAVE][65];

    const float4* a = za4 + (size_t)row0 * 64 + lane;
    const float4* b = zb4 + (size_t)row0 * 64 + lane;

    // Phase 1: stream. Every iteration independent: 2 loads, 4 fma, 1 ds_write.
    #pragma unroll 8
    for (int r = 0; r < ROWS_PER_WAVE; ++r) {
        float4 av = a[(size_t)r * 64];
        float4 bv = b[(size_t)r * 64];
        float t = av.x * bv.x;
        t = fmaf(av.y, bv.y, t);
        t = fmaf(av.z, bv.z, t);
        t = fmaf(av.w, bv.w, t);
        part[wave][r][lane] = t;
    }
    // Same-wave LDS RAW: compiler inserts lgkmcnt wait; no barrier needed
    // (each wave touches only its own part[wave] slab).
    __builtin_amdgcn_s_waitcnt(0);  // vmcnt(0)+lgkmcnt(0); cheap, wave-local

    // Phase 2: transpose read. Lane j sums half of row (j&31):
    // lanes j and j+32 take cols [0,32) and [32,64).
    const int rowIdx = lane & 31;
    const int colBase = (lane >> 5) * 32;
    float s = 0.0f;
    #pragma unroll
    for (int c = 0; c < 32; ++c)
        s += part[wave][rowIdx][colBase + c];

    // Merge halves: lane j<32 adds lane j+32's partial sum.
    float d = s + __shfl_down(s, 32);

    float acc = 0.0f;
    if (lane < 32) {
        int row = row0 + rowIdx;
        float coeff = (row == n - 1) ? (float)(n - 2) : (float)(n - 3);
        acc = coeff * d + expf(d);   // 32 exps in one wave64 v_exp pass
    }

    // Reduce lanes 0..31 -> lane 0.
    #pragma unroll
    for (int off = 16; off > 0; off >>= 1)
        acc += __shfl_down(acc, off);

    __shared__ float smem[WAVES_PER_BLOCK];
    if (lane == 0) smem[wave] = acc;
    __syncthreads();
    if (threadIdx.x == 0) {
        float s2 = 0.0f;
        #pragma unroll
        for (int w = 0; w < WAVES_PER_BLOCK; ++w) s2 += smem[w];
        partial[blockIdx.x] = s2;
    }
}

__global__ __launch_bounds__(256)
void reduce_partials(const float* __restrict__ partial,
                     float* __restrict__ out,
                     int m) {
    const int lane = threadIdx.x & 63;
    const int wave = threadIdx.x >> 6;
    double s = 0.0;
    for (int i = threadIdx.x; i < m; i += 256)
        s += (double)partial[i];
    #pragma unroll
    for (int off = 32; off > 0; off >>= 1)
        s += __shfl_down(s, off);
    __shared__ double smem[4];
    if (lane == 0) smem[wave] = s;
    __syncthreads();
    if (threadIdx.x == 0)
        out[0] = (float)(smem[0] + smem[1] + smem[2] + smem[3]);
}

extern "C" void kernel_launch(void* const* d_in, const int* in_sizes, int n_in,
                              void* d_out, int out_size, void* d_ws, size_t ws_size,
                              hipStream_t stream) {
    const float4* za4 = (const float4*)d_in[0];
    const float4* zb4 = (const float4*)d_in[1];
    float* out = (float*)d_out;
    float* partial = (float*)d_ws;
    const int n = in_sizes[0] / D_DIM;
    const int blocks = n / (ROWS_PER_WAVE * WAVES_PER_BLOCK);  // 512

    dot_loss_partial<<<blocks, 256, 0, stream>>>(za4, zb4, partial, n);
    reduce_partials<<<1, 256, 0, stream>>>(partial, out, blocks);
}